// Round 1
// baseline (1893.101 us; speedup 1.0000x reference)
//
#include <hip/hip_runtime.h>
#include <stdint.h>

#define BS 8
#define NN 400
#define HH 768
#define RR 46
#define MPAD 416
#define NEG_BIG (-1e30f)

typedef _Float16 half8 __attribute__((ext_vector_type(8)));
typedef _Float16 half4v __attribute__((ext_vector_type(4)));
typedef float floatx4 __attribute__((ext_vector_type(4)));

__device__ __forceinline__ void async16(const void* g, void* l) {
  __builtin_amdgcn_global_load_lds((const __attribute__((address_space(1))) uint32_t*)g,
                                   (__attribute__((address_space(3))) uint32_t*)l, 16, 0, 0);
}

// Stage a 128x32 fp16 tile (K-contiguous global layout) into LDS, linear.
// Each wave issues 2 x global_load_lds (1024B each): LDS dest = uniform base + lane*16.
__device__ __forceinline__ void stage_tile(const _Float16* __restrict__ g, int ld, int rowbase,
                                           int maxrow, int kbase, _Float16* lds, int t) {
  int w = t >> 6, lane = t & 63;
#pragma unroll
  for (int j = 0; j < 2; ++j) {
    int chunk = w * 2 + j;             // 0..7, each 512 halves = 1024B
    int eo = chunk * 512 + lane * 8;   // element offset in tile
    int row = eo >> 5;                 // BK=32
    int col = eo & 31;
    int grow = rowbase + row;
    grow = grow > maxrow ? maxrow : grow;  // clamp: garbage rows discarded at store
    async16(g + (size_t)grow * ld + kbase + col, lds + chunk * 512);
  }
}

// One K-step: 8 ds_read_b128 + 16 MFMA per thread-wave (m97 inner loop).
__device__ __forceinline__ void mma_tiles(const _Float16* As, const _Float16* Bs, int lane,
                                          int wr, int wc, floatx4 acc[4][4]) {
  int arow = wr + (lane & 15);
  int brow = wc + (lane & 15);
  int kcol = (lane >> 4) * 8;
  half8 a[4], b[4];
#pragma unroll
  for (int i = 0; i < 4; ++i) a[i] = *(const half8*)&As[(arow + i * 16) * 32 + kcol];
#pragma unroll
  for (int i = 0; i < 4; ++i) b[i] = *(const half8*)&Bs[(brow + i * 16) * 32 + kcol];
#pragma unroll
  for (int i = 0; i < 4; ++i)
#pragma unroll
    for (int j = 0; j < 4; ++j)
      acc[i][j] = __builtin_amdgcn_mfma_f32_16x16x32_f16(a[i], b[j], acc[i][j], 0, 0, 0);
}

// -------- W convert + transpose: W[l][r][h][k] (f32) -> Wt[l][r][k][h] (f16) --------
__global__ __launch_bounds__(256) void conv_w(const float* __restrict__ W, _Float16* __restrict__ Wt) {
  __shared__ float tl[32][33];
  int t = threadIdx.x;
  int lr = blockIdx.y;  // 0..91 = l*46+r
  int tr = blockIdx.x / 24, tc = blockIdx.x % 24;
  const float* src = W + (size_t)lr * HH * HH;
  _Float16* dst = Wt + (size_t)lr * HH * HH;
  int rl = t >> 5, cl = t & 31;
#pragma unroll
  for (int j = 0; j < 4; ++j)
    tl[rl + 8 * j][cl] = src[(size_t)(tr * 32 + rl + 8 * j) * HH + tc * 32 + cl];
  __syncthreads();
#pragma unroll
  for (int j = 0; j < 4; ++j)
    dst[(size_t)(tc * 32 + rl + 8 * j) * HH + tr * 32 + cl] = (_Float16)tl[cl][rl + 8 * j];
}

__global__ void conv_x(const float* __restrict__ f, _Float16* __restrict__ x16) {
  int i = (blockIdx.x * 256 + threadIdx.x) * 4;
  if (i < BS * NN * HH) {
    float4 v = *(const float4*)(f + i);
    half4v h = {(_Float16)v.x, (_Float16)v.y, (_Float16)v.z, (_Float16)v.w};
    *(half4v*)&x16[i] = h;
  }
}

// -------- softmax over m of adj[b,n,m,r] masked by dmask[b,0,m] -> att[b][r][n][m(pad 416)] f16 --------
__global__ __launch_bounds__(256) void att_softmax(const float* __restrict__ adj,
                                                   const float* __restrict__ dmask,
                                                   _Float16* __restrict__ att) {
  __shared__ _Float16 sA[NN * RR];  // 36800 B (f16 keeps static LDS < 64KB)
  __shared__ float sM[NN];
  int t = threadIdx.x;
  int n = blockIdx.x, b = blockIdx.y;
  const float* arow = adj + ((size_t)b * NN + n) * NN * RR;
  for (int i = t; i < NN; i += 256) sM[i] = dmask[b * NN + i];
  for (int i = t * 4; i < NN * RR; i += 1024) {
    float4 v = *(const float4*)(arow + i);
    half4v h = {(_Float16)v.x, (_Float16)v.y, (_Float16)v.z, (_Float16)v.w};
    *(half4v*)&sA[i] = h;
  }
  __syncthreads();
  int lane = t & 63, wid = t >> 6;
  for (int rr = wid; rr < RR; rr += 4) {
    float mx = -3.4e38f;
    for (int m = lane; m < NN; m += 64) {
      float lg = sM[m] > 0.5f ? (float)sA[m * RR + rr] : NEG_BIG;
      mx = fmaxf(mx, lg);
    }
#pragma unroll
    for (int o = 32; o; o >>= 1) mx = fmaxf(mx, __shfl_xor(mx, o));
    float sum = 0.f;
    for (int m = lane; m < NN; m += 64) {
      float lg = sM[m] > 0.5f ? (float)sA[m * RR + rr] : NEG_BIG;
      sum += __expf(lg - mx);
    }
#pragma unroll
    for (int o = 32; o; o >>= 1) sum += __shfl_xor(sum, o);
    float inv = 1.0f / sum;
    _Float16* orow = att + (((size_t)b * RR + rr) * NN + n) * MPAD;
    for (int m = lane; m < MPAD; m += 64) {
      _Float16 v = (_Float16)0.0f;
      if (m < NN) {
        float lg = sM[m] > 0.5f ? (float)sA[m * RR + rr] : NEG_BIG;
        v = (_Float16)(__expf(lg - mx) * inv);
      }
      orow[m] = v;
    }
  }
}

// -------- GEMM C: h1[n][k] = x[b][n][:] @ W_r ; store TRANSPOSED h1T[k][m(pad 416)] f16 --------
__global__ __launch_bounds__(256) void gemm_xw(const _Float16* __restrict__ x16,
                                               const _Float16* __restrict__ Wt,
                                               _Float16* __restrict__ h1T, int layer, int r0, int RC) {
  __shared__ _Float16 As[128 * 32];
  __shared__ _Float16 Bs[128 * 32];
  __shared__ _Float16 outl[128 * 136];  // [col][row+8 pad] for transpose epilogue
  int t = threadIdx.x;
  int b = blockIdx.z, y = blockIdx.y, r = r0 + y;
  int mtile = blockIdx.x / 6, ntile = blockIdx.x % 6;
  const _Float16* A = x16 + (size_t)b * NN * HH;
  const _Float16* Bp = Wt + ((size_t)layer * RR + r) * HH * HH;
  int lane = t & 63, w = t >> 6;
  int wr = (w >> 1) * 64, wc = (w & 1) * 64;
  floatx4 acc[4][4] = {};
  for (int ks = 0; ks < 24; ++ks) {
    stage_tile(A, HH, mtile * 128, NN - 1, ks * 32, As, t);
    stage_tile(Bp, HH, ntile * 128, HH - 1, ks * 32, Bs, t);
    __syncthreads();
    mma_tiles(As, Bs, lane, wr, wc, acc);
    __syncthreads();
  }
  // transpose epilogue: acc -> outl[col][row], zero rows 400..415 (K-pad for GEMM D)
#pragma unroll
  for (int i = 0; i < 4; ++i) {
#pragma unroll
    for (int j = 0; j < 4; ++j) {
      int rl = wr + i * 16 + (lane >> 4) * 4;
      int cl = wc + j * 16 + (lane & 15);
      int growbase = mtile * 128 + rl;
      half4v v;
#pragma unroll
      for (int q = 0; q < 4; ++q)
        v[q] = (growbase + q < NN) ? (_Float16)acc[i][j][q] : (_Float16)0.0f;
      *(half4v*)&outl[cl * 136 + rl] = v;
    }
  }
  __syncthreads();
  _Float16* outp = h1T + ((size_t)b * RC + y) * HH * MPAD;
#pragma unroll
  for (int pass = 0; pass < 8; ++pass) {
    int c = pass * 16 + (t >> 4);
    int ml = (t & 15) * 8;
    int gm = mtile * 128 + ml;
    if (gm < MPAD) {
      half8 v = *(const half8*)&outl[c * 136 + ml];
      int gn = ntile * 128 + c;
      *(half8*)&outp[(size_t)gn * MPAD + gm] = v;
    }
  }
}

// -------- GEMM D: addition[b][n][k] += relu(att[b][r] @ h1) over r (fp32 atomics) --------
__global__ __launch_bounds__(256) void gemm_att(const _Float16* __restrict__ att,
                                                const _Float16* __restrict__ h1T,
                                                float* __restrict__ addition, int r0, int RC) {
  __shared__ _Float16 As[128 * 32];
  __shared__ _Float16 Bs[128 * 32];
  int t = threadIdx.x;
  int b = blockIdx.z, y = blockIdx.y, r = r0 + y;
  int mtile = blockIdx.x / 6, ntile = blockIdx.x % 6;
  const _Float16* A = att + ((size_t)b * RR + r) * NN * MPAD;
  const _Float16* Bp = h1T + ((size_t)b * RC + y) * HH * MPAD;
  int lane = t & 63, w = t >> 6;
  int wr = (w >> 1) * 64, wc = (w & 1) * 64;
  floatx4 acc[4][4] = {};
  for (int ks = 0; ks < 13; ++ks) {
    stage_tile(A, MPAD, mtile * 128, NN - 1, ks * 32, As, t);
    stage_tile(Bp, MPAD, ntile * 128, HH - 1, ks * 32, Bs, t);
    __syncthreads();
    mma_tiles(As, Bs, lane, wr, wc, acc);
    __syncthreads();
  }
  float* outp = addition + (size_t)b * NN * HH;
#pragma unroll
  for (int i = 0; i < 4; ++i) {
    int rl = wr + i * 16 + (lane >> 4) * 4;
    int grow = mtile * 128 + rl;
#pragma unroll
    for (int j = 0; j < 4; ++j) {
      int gcol = ntile * 128 + wc + j * 16 + (lane & 15);
#pragma unroll
      for (int q = 0; q < 4; ++q) {
        if (grow + q < NN)
          atomicAdd(&outp[(size_t)(grow + q) * HH + gcol], fmaxf(acc[i][j][q], 0.0f));
      }
    }
  }
}

// -------- LayerNorm: z = relu(addition)/R, LN over H; write f16 x_next + f32 d_out --------
__global__ __launch_bounds__(256) void lnorm(const float* __restrict__ add, _Float16* __restrict__ x16,
                                             float* __restrict__ out) {
  int row = blockIdx.x;  // 0..3199
  const float* a = add + (size_t)row * HH;
  int t = threadIdx.x;
  float v[3];
  float s = 0.f, s2 = 0.f;
#pragma unroll
  for (int j = 0; j < 3; ++j) {
    v[j] = fmaxf(a[t + j * 256], 0.f) * (1.0f / RR);
    s += v[j];
    s2 += v[j] * v[j];
  }
#pragma unroll
  for (int o = 32; o; o >>= 1) {
    s += __shfl_xor(s, o);
    s2 += __shfl_xor(s2, o);
  }
  __shared__ float rs[4], rs2[4];
  int lane = t & 63, wid = t >> 6;
  if (!lane) {
    rs[wid] = s;
    rs2[wid] = s2;
  }
  __syncthreads();
  s = rs[0] + rs[1] + rs[2] + rs[3];
  s2 = rs2[0] + rs2[1] + rs2[2] + rs2[3];
  float mu = s * (1.0f / HH);
  float var = s2 * (1.0f / HH) - mu * mu;
  float rstd = rsqrtf(var + 1e-5f);
#pragma unroll
  for (int j = 0; j < 3; ++j) {
    float o = (v[j] - mu) * rstd;
    out[(size_t)row * HH + t + j * 256] = o;
    x16[(size_t)row * HH + t + j * 256] = (_Float16)o;
  }
}

extern "C" void kernel_launch(void* const* d_in, const int* in_sizes, int n_in,
                              void* d_out, int out_size, void* d_ws, size_t ws_size,
                              hipStream_t stream) {
  const float* adj = (const float*)d_in[0];
  const float* feature = (const float*)d_in[1];
  const float* dmask = (const float*)d_in[2];
  const float* W = (const float*)d_in[3];
  float* out = (float*)d_out;

  uintptr_t base = (uintptr_t)d_ws;
  uintptr_t p = base;
  auto alloc = [&](size_t bytes) -> void* {
    uintptr_t q = (p + 255) & ~(uintptr_t)255;
    p = q + bytes;
    return (void*)q;
  };
  _Float16* att = (_Float16*)alloc((size_t)BS * RR * NN * MPAD * 2);  // 122.5 MB
  _Float16* Wt = (_Float16*)alloc((size_t)2 * RR * HH * HH * 2);      // 108.5 MB
  _Float16* x16 = (_Float16*)alloc((size_t)BS * NN * HH * 2);         // 4.9 MB
  float* addition = (float*)alloc((size_t)BS * NN * HH * 4);          // 9.8 MB
  size_t used = p - base;
  size_t perR = (size_t)BS * HH * MPAD * 2 + 256;
  size_t avail = ws_size > used ? ws_size - used : 0;
  int RC = (int)(avail / perR);
  if (RC > 12) RC = 12;  // keep h1T chunk (~61MB) L3-resident between C and D
  if (RC < 1) RC = 1;
  _Float16* h1T = (_Float16*)alloc((size_t)RC * BS * HH * MPAD * 2);

  conv_w<<<dim3(576, 2 * RR), 256, 0, stream>>>(W, Wt);
  conv_x<<<(BS * NN * HH / 4 + 255) / 256, 256, 0, stream>>>(feature, x16);
  att_softmax<<<dim3(NN, BS), 256, 0, stream>>>(adj, dmask, att);

  for (int layer = 0; layer < 2; ++layer) {
    hipMemsetAsync(addition, 0, (size_t)BS * NN * HH * 4, stream);
    for (int r0 = 0; r0 < RR; r0 += RC) {
      int rc = RR - r0 < RC ? RR - r0 : RC;
      gemm_xw<<<dim3(24, rc, BS), 256, 0, stream>>>(x16, Wt, h1T, layer, r0, RC);
      gemm_att<<<dim3(24, rc, BS), 256, 0, stream>>>(att, h1T, addition, r0, RC);
    }
    lnorm<<<BS * NN, 256, 0, stream>>>(addition, x16, out);
  }
}

// Round 2
// 1825.568 us; speedup vs baseline: 1.0370x; 1.0370x over previous
//
#include <hip/hip_runtime.h>
#include <stdint.h>

#define BS 8
#define NN 400
#define HH 768
#define RR 46
#define MPAD 416
#define MFLAT 3200   // B*N flattened, = 25 * 128 exactly
#define LDW 3216     // h1T row width: 3200 + 16 pad (16B-aligned, absorbs b=7 overread)
#define PADM 402     // LDS row pad for softmax (even, odd/2 stride vs banks)

typedef _Float16 half8 __attribute__((ext_vector_type(8)));
typedef _Float16 half4v __attribute__((ext_vector_type(4)));
typedef float floatx4 __attribute__((ext_vector_type(4)));

__device__ __forceinline__ void async16(const void* g, void* l) {
  __builtin_amdgcn_global_load_lds((const __attribute__((address_space(1))) uint32_t*)g,
                                   (__attribute__((address_space(3))) uint32_t*)l, 16, 0, 0);
}

// Stage a 128x32 fp16 tile (K-contiguous global layout) into LDS, linear.
__device__ __forceinline__ void stage_tile(const _Float16* __restrict__ g, int ld, int rowbase,
                                           int maxrow, int kbase, _Float16* lds, int t) {
  int w = t >> 6, lane = t & 63;
#pragma unroll
  for (int j = 0; j < 2; ++j) {
    int chunk = w * 2 + j;             // 0..7, each 512 halves = 1024B
    int eo = chunk * 512 + lane * 8;
    int row = eo >> 5;                 // BK=32
    int col = eo & 31;
    int grow = rowbase + row;
    grow = grow > maxrow ? maxrow : grow;  // clamp: garbage discarded at store
    async16(g + (size_t)grow * ld + kbase + col, lds + chunk * 512);
  }
}

// One K-step: 8 ds_read_b128 + 16 MFMA per wave (m97 inner loop).
__device__ __forceinline__ void mma_tiles(const _Float16* As, const _Float16* Bs, int lane,
                                          int wr, int wc, floatx4 acc[4][4]) {
  int arow = wr + (lane & 15);
  int brow = wc + (lane & 15);
  int kcol = (lane >> 4) * 8;
  half8 a[4], b[4];
#pragma unroll
  for (int i = 0; i < 4; ++i) a[i] = *(const half8*)&As[(arow + i * 16) * 32 + kcol];
#pragma unroll
  for (int i = 0; i < 4; ++i) b[i] = *(const half8*)&Bs[(brow + i * 16) * 32 + kcol];
#pragma unroll
  for (int i = 0; i < 4; ++i)
#pragma unroll
    for (int j = 0; j < 4; ++j)
      acc[i][j] = __builtin_amdgcn_mfma_f32_16x16x32_f16(a[i], b[j], acc[i][j], 0, 0, 0);
}

// -------- W convert + transpose: W[l][r][h][k] (f32) -> Wt[l][r][k][h] (f16) --------
__global__ __launch_bounds__(256) void conv_w(const float* __restrict__ W, _Float16* __restrict__ Wt) {
  __shared__ float tl[32][33];
  int t = threadIdx.x;
  int lr = blockIdx.y;
  int tr = blockIdx.x / 24, tc = blockIdx.x % 24;
  const float* src = W + (size_t)lr * HH * HH;
  _Float16* dst = Wt + (size_t)lr * HH * HH;
  int rl = t >> 5, cl = t & 31;
#pragma unroll
  for (int j = 0; j < 4; ++j)
    tl[rl + 8 * j][cl] = src[(size_t)(tr * 32 + rl + 8 * j) * HH + tc * 32 + cl];
  __syncthreads();
#pragma unroll
  for (int j = 0; j < 4; ++j)
    dst[(size_t)(tc * 32 + rl + 8 * j) * HH + tr * 32 + cl] = (_Float16)tl[cl][rl + 8 * j];
}

__global__ void conv_x(const float* __restrict__ f, _Float16* __restrict__ x16) {
  int i = (blockIdx.x * 256 + threadIdx.x) * 4;
  if (i < MFLAT * HH) {
    float4 v = *(const float4*)(f + i);
    half4v h = {(_Float16)v.x, (_Float16)v.y, (_Float16)v.z, (_Float16)v.w};
    *(half4v*)&x16[i] = h;
  }
}

// -------- softmax: no-max-pass (logits in [0,1] or masked->0), exp at staging --------
// adj[b,n,m,r] f32 -> att[b][r][n][m(pad416)] f16
__global__ __launch_bounds__(512) void att_softmax(const float* __restrict__ adj,
                                                   const float* __restrict__ dmask,
                                                   _Float16* __restrict__ att) {
  __shared__ _Float16 sE[RR * PADM];  // 36984 B, [r][m] transposed
  __shared__ float sM[NN];
  int t = threadIdx.x;
  int n = blockIdx.x, b = blockIdx.y;
  const float* arow = adj + ((size_t)b * NN + n) * NN * RR;
  for (int i = t; i < NN; i += 512) sM[i] = dmask[b * NN + i];
  __syncthreads();
  for (int e0 = t * 4; e0 < NN * RR; e0 += 2048) {
    float4 v = *(const float4*)(arow + e0);
    float vv[4] = {v.x, v.y, v.z, v.w};
#pragma unroll
    for (int j = 0; j < 4; ++j) {
      int e = e0 + j;
      int m = e / RR;          // magic-mul
      int r = e - m * RR;
      float val = sM[m] > 0.5f ? __expf(vv[j]) : 0.0f;
      sE[r * PADM + m] = (_Float16)val;
    }
  }
  __syncthreads();
  int lane = t & 63, wid = t >> 6;
  for (int r = wid; r < RR; r += 8) {
    const _Float16* row = &sE[r * PADM];
    float s = 0.f;
    for (int m = lane; m < NN; m += 64) s += (float)row[m];
#pragma unroll
    for (int o = 32; o; o >>= 1) s += __shfl_xor(s, o);
    float inv = 1.0f / s;
    _Float16* orow = att + (((size_t)b * RR + r) * NN + n) * MPAD;
    for (int m2 = lane * 2; m2 < MPAD; m2 += 128) {
      _Float16 lo = (_Float16)0.f, hi = (_Float16)0.f;
      if (m2 < NN) lo = (_Float16)((float)row[m2] * inv);
      if (m2 + 1 < NN) hi = (_Float16)((float)row[m2 + 1] * inv);
      union { _Float16 h[2]; uint32_t u; } pk;
      pk.h[0] = lo; pk.h[1] = hi;
      *(uint32_t*)&orow[m2] = pk.u;
    }
  }
}

// -------- GEMM C: h1T[r][k][gm] = (x_flat @ W_r)^T, flat M=3200, no pad waste --------
__global__ __launch_bounds__(256) void gemm_xw(const _Float16* __restrict__ x16,
                                               const _Float16* __restrict__ Wt,
                                               _Float16* __restrict__ h1T, int layer, int r0, int rbase) {
  __shared__ _Float16 As[128 * 32];
  __shared__ _Float16 Bs[128 * 32];
  __shared__ _Float16 outl[128 * 136];
  int t = threadIdx.x;
  int r = r0 + blockIdx.y;
  int mtile = blockIdx.x / 6, ntile = blockIdx.x % 6;  // 25 x 6
  const _Float16* A = x16;
  const _Float16* Bp = Wt + ((size_t)layer * RR + r) * HH * HH;
  int lane = t & 63, w = t >> 6;
  int wr = (w >> 1) * 64, wc = (w & 1) * 64;
  floatx4 acc[4][4] = {};
  for (int ks = 0; ks < 24; ++ks) {
    stage_tile(A, HH, mtile * 128, MFLAT - 1, ks * 32, As, t);
    stage_tile(Bp, HH, ntile * 128, HH - 1, ks * 32, Bs, t);
    __syncthreads();
    mma_tiles(As, Bs, lane, wr, wc, acc);
    __syncthreads();
  }
#pragma unroll
  for (int i = 0; i < 4; ++i) {
#pragma unroll
    for (int j = 0; j < 4; ++j) {
      int rl = wr + i * 16 + (lane >> 4) * 4;
      int cl = wc + j * 16 + (lane & 15);
      half4v v = {(_Float16)acc[i][j][0], (_Float16)acc[i][j][1],
                  (_Float16)acc[i][j][2], (_Float16)acc[i][j][3]};
      *(half4v*)&outl[cl * 136 + rl] = v;
    }
  }
  __syncthreads();
  _Float16* outp = h1T + (size_t)(r - rbase) * HH * LDW;
#pragma unroll
  for (int pass = 0; pass < 8; ++pass) {
    int c = pass * 16 + (t >> 4);
    int ml = (t & 15) * 8;
    int gm = mtile * 128 + ml;
    int gn = ntile * 128 + c;
    half8 v = *(const half8*)&outl[c * 136 + ml];
    *(half8*)&outp[(size_t)gn * LDW + gm] = v;
  }
}

// -------- GEMM D: partial[g] = sum_{r in group g} relu(att[b,r] @ h1[r]); no atomics --------
__global__ __launch_bounds__(256) void gemm_att(const _Float16* __restrict__ att,
                                                const _Float16* __restrict__ h1T,
                                                float* __restrict__ partials, size_t psz,
                                                int rs, int RG, int rtot, int rbase, int accflag) {
  __shared__ _Float16 As[128 * 32];
  __shared__ _Float16 Bs[128 * 32];
  int t = threadIdx.x;
  int b = blockIdx.z, g = blockIdx.y;
  int mtile = blockIdx.x / 6, ntile = blockIdx.x % 6;
  int rbeg = rs + g * RG;
  int rend = rtot < rbeg + RG ? rtot : rbeg + RG;
  float* part = partials + (size_t)g * psz;
  int lane = t & 63, w = t >> 6;
  int wr = (w >> 1) * 64, wc = (w & 1) * 64;
  floatx4 sum[4][4] = {};
  for (int r = rbeg; r < rend; ++r) {
    const _Float16* A = att + ((size_t)b * RR + r) * NN * MPAD;
    const _Float16* Bp = h1T + (size_t)(r - rbase) * HH * LDW + b * NN;
    floatx4 acc[4][4] = {};
    for (int ks = 0; ks < 13; ++ks) {
      stage_tile(A, MPAD, mtile * 128, NN - 1, ks * 32, As, t);
      stage_tile(Bp, LDW, ntile * 128, HH - 1, ks * 32, Bs, t);
      __syncthreads();
      mma_tiles(As, Bs, lane, wr, wc, acc);
      __syncthreads();
    }
#pragma unroll
    for (int i = 0; i < 4; ++i)
#pragma unroll
      for (int j = 0; j < 4; ++j)
#pragma unroll
        for (int q = 0; q < 4; ++q)
          sum[i][j][q] += fmaxf(acc[i][j][q], 0.0f);
  }
#pragma unroll
  for (int i = 0; i < 4; ++i) {
    int rl = wr + i * 16 + (lane >> 4) * 4;
    int grow = mtile * 128 + rl;
#pragma unroll
    for (int j = 0; j < 4; ++j) {
      int gcol = ntile * 128 + wc + j * 16 + (lane & 15);
#pragma unroll
      for (int q = 0; q < 4; ++q) {
        if (grow + q < NN) {
          size_t idx = ((size_t)b * NN + grow + q) * HH + gcol;
          float v = sum[i][j][q];
          if (accflag) v += part[idx];
          part[idx] = v;
        }
      }
    }
  }
}

// -------- LayerNorm over H of z = relu(sum_g partial[g]) / R --------
__global__ __launch_bounds__(256) void lnorm(const float* __restrict__ partials, size_t psz, int np,
                                             _Float16* __restrict__ x16, float* __restrict__ out) {
  int row = blockIdx.x;  // 0..3199
  int t = threadIdx.x;
  float v[3];
  float s = 0.f, s2 = 0.f;
#pragma unroll
  for (int j = 0; j < 3; ++j) {
    float a = 0.f;
    for (int gidx = 0; gidx < np; ++gidx) a += partials[(size_t)gidx * psz + (size_t)row * HH + t + j * 256];
    v[j] = fmaxf(a, 0.f) * (1.0f / RR);
    s += v[j];
    s2 += v[j] * v[j];
  }
#pragma unroll
  for (int o = 32; o; o >>= 1) {
    s += __shfl_xor(s, o);
    s2 += __shfl_xor(s2, o);
  }
  __shared__ float rs_[4], rs2_[4];
  int lane = t & 63, wid = t >> 6;
  if (!lane) { rs_[wid] = s; rs2_[wid] = s2; }
  __syncthreads();
  s = rs_[0] + rs_[1] + rs_[2] + rs_[3];
  s2 = rs2_[0] + rs2_[1] + rs2_[2] + rs2_[3];
  float mu = s * (1.0f / HH);
  float var = s2 * (1.0f / HH) - mu * mu;
  float rstd = rsqrtf(var + 1e-5f);
#pragma unroll
  for (int j = 0; j < 3; ++j) {
    float o = (v[j] - mu) * rstd;
    out[(size_t)row * HH + t + j * 256] = o;
    x16[(size_t)row * HH + t + j * 256] = (_Float16)o;
  }
}

extern "C" void kernel_launch(void* const* d_in, const int* in_sizes, int n_in,
                              void* d_out, int out_size, void* d_ws, size_t ws_size,
                              hipStream_t stream) {
  const float* adj = (const float*)d_in[0];
  const float* feature = (const float*)d_in[1];
  const float* dmask = (const float*)d_in[2];
  const float* W = (const float*)d_in[3];
  float* out = (float*)d_out;

  uintptr_t base = (uintptr_t)d_ws;
  uintptr_t p = base;
  auto alloc = [&](size_t bytes) -> void* {
    uintptr_t q = (p + 255) & ~(uintptr_t)255;
    p = q + bytes;
    return (void*)q;
  };
  _Float16* att = (_Float16*)alloc((size_t)BS * RR * NN * MPAD * 2);  // 122.5 MB
  _Float16* Wt = (_Float16*)alloc((size_t)2 * RR * HH * HH * 2);      // 108.5 MB
  _Float16* x16 = (_Float16*)alloc((size_t)MFLAT * HH * 2);           // 4.9 MB
  size_t psz = (size_t)MFLAT * HH;
  float* partials = (float*)alloc(4 * psz * 4);                       // 39.3 MB
  size_t used = p - base;
  size_t perR = (size_t)HH * LDW * 2;                                 // 4.94 MB / r
  size_t avail = ws_size > used ? ws_size - used : 0;
  int RCmax = (int)(avail / perR);
  if (RCmax > RR) RCmax = RR;
  if (RCmax < 1) RCmax = 1;
  _Float16* h1T = (_Float16*)alloc((size_t)RCmax * perR);

  conv_w<<<dim3(576, 2 * RR), 256, 0, stream>>>(W, Wt);
  conv_x<<<(MFLAT * HH / 4 + 255) / 256, 256, 0, stream>>>(feature, x16);
  att_softmax<<<dim3(NN, BS), 512, 0, stream>>>(adj, dmask, att);

  for (int layer = 0; layer < 2; ++layer) {
    if (RCmax >= RR) {
      // full path: one gemm_xw + one gemm_att launch per layer
      gemm_xw<<<dim3(150, RR, 1), 256, 0, stream>>>(x16, Wt, h1T, layer, 0, 0);
      gemm_att<<<dim3(24, 4, BS), 256, 0, stream>>>(att, h1T, partials, psz, 0, 12, RR, 0, 0);
      lnorm<<<MFLAT, 256, 0, stream>>>(partials, psz, 4, x16, out);
    } else {
      for (int r0 = 0; r0 < RR; r0 += RCmax) {
        int rc = RR - r0 < RCmax ? RR - r0 : RCmax;
        gemm_xw<<<dim3(150, rc, 1), 256, 0, stream>>>(x16, Wt, h1T, layer, r0, r0);
        gemm_att<<<dim3(24, 1, BS), 256, 0, stream>>>(att, h1T, partials, psz, r0, rc, r0 + rc, r0, r0 > 0);
      }
      lnorm<<<MFLAT, 256, 0, stream>>>(partials, psz, 1, x16, out);
    }
  }
}

// Round 3
// 1212.327 us; speedup vs baseline: 1.5615x; 1.5058x over previous
//
#include <hip/hip_runtime.h>
#include <stdint.h>

#define BS 8
#define NN 400
#define HH 768
#define RR 46
#define MPAD 416
#define MFLAT 3200   // B*N flattened, = 25 * 128 exactly
#define LDW 3216     // h1T row width: 3200 + 16 pad (16B-aligned, absorbs gemm_att b=7 K-overread)
#define PADM 402     // LDS row pad for softmax

typedef _Float16 half8 __attribute__((ext_vector_type(8)));
typedef _Float16 half4v __attribute__((ext_vector_type(4)));
typedef float floatx4 __attribute__((ext_vector_type(4)));

__device__ __forceinline__ void async16(const void* g, void* l) {
  __builtin_amdgcn_global_load_lds((const __attribute__((address_space(1))) uint32_t*)g,
                                   (__attribute__((address_space(3))) uint32_t*)l, 16, 0, 0);
}

// bijective XCD swizzle (m204): flat blockIdx -> work id s.t. consecutive work ids
// share an XCD (hardware round-robins flat id % 8 across XCDs).
__device__ __forceinline__ int xcd_work(int flat, int nwg) {
  int q = nwg >> 3, rem = nwg & 7;
  int xcd = flat & 7, slot = flat >> 3;
  return (xcd < rem ? xcd * (q + 1) : rem * (q + 1) + (xcd - rem) * q) + slot;
}

// Stage a 128x32 fp16 tile (K-contiguous global layout) into LDS, linear.
__device__ __forceinline__ void stage_tile(const _Float16* __restrict__ g, int ld, int rowbase,
                                           int maxrow, int kbase, _Float16* lds, int t) {
  int w = t >> 6, lane = t & 63;
#pragma unroll
  for (int j = 0; j < 2; ++j) {
    int chunk = w * 2 + j;             // 0..7, each 512 halves = 1024B
    int eo = chunk * 512 + lane * 8;
    int row = eo >> 5;                 // BK=32
    int col = eo & 31;
    int grow = rowbase + row;
    grow = grow > maxrow ? maxrow : grow;  // clamp: garbage discarded at store
    async16(g + (size_t)grow * ld + kbase + col, lds + chunk * 512);
  }
}

// One K-step: 8 ds_read_b128 + 16 MFMA per wave (m97 inner loop).
__device__ __forceinline__ void mma_tiles(const _Float16* As, const _Float16* Bs, int lane,
                                          int wr, int wc, floatx4 acc[4][4]) {
  int arow = wr + (lane & 15);
  int brow = wc + (lane & 15);
  int kcol = (lane >> 4) * 8;
  half8 a[4], b[4];
#pragma unroll
  for (int i = 0; i < 4; ++i) a[i] = *(const half8*)&As[(arow + i * 16) * 32 + kcol];
#pragma unroll
  for (int i = 0; i < 4; ++i) b[i] = *(const half8*)&Bs[(brow + i * 16) * 32 + kcol];
#pragma unroll
  for (int i = 0; i < 4; ++i)
#pragma unroll
    for (int j = 0; j < 4; ++j)
      acc[i][j] = __builtin_amdgcn_mfma_f32_16x16x32_f16(a[i], b[j], acc[i][j], 0, 0, 0);
}

// -------- W convert + transpose: W[l][r][h][k] (f32) -> Wt[l][r][k][h] (f16) --------
__global__ __launch_bounds__(256) void conv_w(const float* __restrict__ W, _Float16* __restrict__ Wt) {
  __shared__ float tl[32][33];
  int t = threadIdx.x;
  int lr = blockIdx.y;
  int tr = blockIdx.x / 24, tc = blockIdx.x % 24;
  const float* src = W + (size_t)lr * HH * HH;
  _Float16* dst = Wt + (size_t)lr * HH * HH;
  int rl = t >> 5, cl = t & 31;
#pragma unroll
  for (int j = 0; j < 4; ++j)
    tl[rl + 8 * j][cl] = src[(size_t)(tr * 32 + rl + 8 * j) * HH + tc * 32 + cl];
  __syncthreads();
#pragma unroll
  for (int j = 0; j < 4; ++j)
    dst[(size_t)(tc * 32 + rl + 8 * j) * HH + tr * 32 + cl] = (_Float16)tl[cl][rl + 8 * j];
}

__global__ void conv_x(const float* __restrict__ f, _Float16* __restrict__ x16) {
  int i = (blockIdx.x * 256 + threadIdx.x) * 4;
  if (i < MFLAT * HH) {
    float4 v = *(const float4*)(f + i);
    half4v h = {(_Float16)v.x, (_Float16)v.y, (_Float16)v.z, (_Float16)v.w};
    *(half4v*)&x16[i] = h;
  }
}

// -------- softmax: no-max-pass (logits in [0,1] or masked->0), exp at staging --------
__global__ __launch_bounds__(512) void att_softmax(const float* __restrict__ adj,
                                                   const float* __restrict__ dmask,
                                                   _Float16* __restrict__ att) {
  __shared__ _Float16 sE[RR * PADM];
  __shared__ float sM[NN];
  int t = threadIdx.x;
  int n = blockIdx.x, b = blockIdx.y;
  const float* arow = adj + ((size_t)b * NN + n) * NN * RR;
  for (int i = t; i < NN; i += 512) sM[i] = dmask[b * NN + i];
  __syncthreads();
  for (int e0 = t * 4; e0 < NN * RR; e0 += 2048) {
    float4 v = *(const float4*)(arow + e0);
    float vv[4] = {v.x, v.y, v.z, v.w};
#pragma unroll
    for (int j = 0; j < 4; ++j) {
      int e = e0 + j;
      int m = e / RR;
      int r = e - m * RR;
      float val = sM[m] > 0.5f ? __expf(vv[j]) : 0.0f;
      sE[r * PADM + m] = (_Float16)val;
    }
  }
  __syncthreads();
  int lane = t & 63, wid = t >> 6;
  for (int r = wid; r < RR; r += 8) {
    const _Float16* row = &sE[r * PADM];
    float s = 0.f;
    for (int m = lane; m < NN; m += 64) s += (float)row[m];
#pragma unroll
    for (int o = 32; o; o >>= 1) s += __shfl_xor(s, o);
    float inv = 1.0f / s;
    _Float16* orow = att + (((size_t)b * RR + r) * NN + n) * MPAD;
    for (int m2 = lane * 2; m2 < MPAD; m2 += 128) {
      _Float16 lo = (_Float16)0.f, hi = (_Float16)0.f;
      if (m2 < NN) lo = (_Float16)((float)row[m2] * inv);
      if (m2 + 1 < NN) hi = (_Float16)((float)row[m2 + 1] * inv);
      union { _Float16 h[2]; uint32_t u; } pk;
      pk.h[0] = lo; pk.h[1] = hi;
      *(uint32_t*)&orow[m2] = pk.u;
    }
  }
}

// -------- GEMM C: h1T[r][k][gm] = (x_flat @ W_r)^T; 2-phase pipeline + XCD swizzle --------
__global__ __launch_bounds__(256) void gemm_xw(const _Float16* __restrict__ x16,
                                               const _Float16* __restrict__ Wt,
                                               _Float16* __restrict__ h1T, int layer, int r0, int rbase) {
  __shared__ __align__(16) char smraw[34816];  // 2x(As+Bs)=32KB dbuf; epilogue outl (34.8KB) aliases
  int t = threadIdx.x;
  int work = xcd_work(blockIdx.x, gridDim.x);
  int r_i = work / 150;
  int rem = work - r_i * 150;
  int r = r0 + r_i;
  int mtile = rem / 6, ntile = rem % 6;
  const _Float16* A = x16;
  const _Float16* Bp = Wt + ((size_t)layer * RR + r) * HH * HH;
  int lane = t & 63, w = t >> 6;
  int wr = (w >> 1) * 64, wc = (w & 1) * 64;
  floatx4 acc[4][4] = {};
  // prologue: stage ks=0 into buf0
  stage_tile(A, HH, mtile * 128, MFLAT - 1, 0, (_Float16*)smraw, t);
  stage_tile(Bp, HH, ntile * 128, HH - 1, 0, (_Float16*)(smraw + 8192), t);
  __syncthreads();
  for (int ks = 0; ks < 24; ++ks) {
    int cur = ks & 1;
    if (ks < 23) {
      char* nb = smraw + ((cur ^ 1) << 14);
      stage_tile(A, HH, mtile * 128, MFLAT - 1, (ks + 1) * 32, (_Float16*)nb, t);
      stage_tile(Bp, HH, ntile * 128, HH - 1, (ks + 1) * 32, (_Float16*)(nb + 8192), t);
    }
    char* cb = smraw + (cur << 14);
    mma_tiles((const _Float16*)cb, (const _Float16*)(cb + 8192), lane, wr, wc, acc);
    __syncthreads();  // drains stage (vmcnt) + ds_reads; next iter overwrites cb
  }
  // transpose epilogue (outl aliases staging LDS — all staging consumed by final barrier)
  _Float16* outl = (_Float16*)smraw;
#pragma unroll
  for (int i = 0; i < 4; ++i) {
#pragma unroll
    for (int j = 0; j < 4; ++j) {
      int rl = wr + i * 16 + (lane >> 4) * 4;
      int cl = wc + j * 16 + (lane & 15);
      half4v v = {(_Float16)acc[i][j][0], (_Float16)acc[i][j][1],
                  (_Float16)acc[i][j][2], (_Float16)acc[i][j][3]};
      *(half4v*)&outl[cl * 136 + rl] = v;
    }
  }
  __syncthreads();
  _Float16* outp = h1T + (size_t)(r - rbase) * HH * LDW;
#pragma unroll
  for (int pass = 0; pass < 8; ++pass) {
    int c = pass * 16 + (t >> 4);
    int ml = (t & 15) * 8;
    int gm = mtile * 128 + ml;
    int gn = ntile * 128 + c;
    half8 v = *(const half8*)&outl[c * 136 + ml];
    *(half8*)&outp[(size_t)gn * LDW + gm] = v;
  }
}

// -------- GEMM D: streaming over r-group with continuous 2-phase prefetch; no atomics --------
__global__ __launch_bounds__(256) void gemm_att(const _Float16* __restrict__ att,
                                                const _Float16* __restrict__ h1T,
                                                float* __restrict__ partials, size_t psz,
                                                int rs, int RG, int rtot, int rbase, int accflag,
                                                int ngroups) {
  __shared__ __align__(16) char smraw[32768];  // 2 x (As 8KB + Bs 8KB)
  int t = threadIdx.x;
  int work = xcd_work(blockIdx.x, gridDim.x);
  int ntile = work % 6;
  int tmp = work / 6;
  int mtile = tmp & 3; tmp >>= 2;
  int g = tmp % ngroups;
  int b = tmp / ngroups;
  int rbeg = rs + g * RG;
  int rend = rtot < rbeg + RG ? rtot : rbeg + RG;
  int nr = rend - rbeg;
  float* part = partials + (size_t)g * psz;
  int lane = t & 63, w = t >> 6;
  int wr = (w >> 1) * 64, wc = (w & 1) * 64;
  floatx4 acc[4][4] = {}, sum[4][4] = {};
  const _Float16* A0 = att + ((size_t)b * RR + rbeg) * NN * MPAD;   // +NN*MPAD per r
  const _Float16* B0 = h1T + (size_t)(rbeg - rbase) * HH * LDW + b * NN;  // +HH*LDW per r
  // prologue: stage (r=rbeg, ks=0) into buf0
  stage_tile(A0, MPAD, mtile * 128, NN - 1, 0, (_Float16*)smraw, t);
  stage_tile(B0, LDW, ntile * 128, HH - 1, 0, (_Float16*)(smraw + 8192), t);
  __syncthreads();
  int total = nr * 13;
  const _Float16* nsA = A0;  // r-pointer of NEXT stage
  const _Float16* nsB = B0;
  int nsk = 1;               // ks of NEXT stage
  int cks = 0;               // ks of current compute
  for (int s = 0; s < total; ++s) {
    int cur = s & 1;
    if (s + 1 < total) {
      char* nb = smraw + ((cur ^ 1) << 14);
      stage_tile(nsA, MPAD, mtile * 128, NN - 1, nsk * 32, (_Float16*)nb, t);
      stage_tile(nsB, LDW, ntile * 128, HH - 1, nsk * 32, (_Float16*)(nb + 8192), t);
      if (++nsk == 13) { nsk = 0; nsA += (size_t)NN * MPAD; nsB += (size_t)HH * LDW; }
    }
    char* cb = smraw + (cur << 14);
    mma_tiles((const _Float16*)cb, (const _Float16*)(cb + 8192), lane, wr, wc, acc);
    if (cks == 12) {  // end of this r: fold relu(acc) into sum, reset acc
#pragma unroll
      for (int i = 0; i < 4; ++i)
#pragma unroll
        for (int j = 0; j < 4; ++j) {
#pragma unroll
          for (int q2 = 0; q2 < 4; ++q2) sum[i][j][q2] += fmaxf(acc[i][j][q2], 0.0f);
          acc[i][j] = (floatx4){0.f, 0.f, 0.f, 0.f};
        }
    }
    __syncthreads();
    cks = cks == 12 ? 0 : cks + 1;
  }
#pragma unroll
  for (int i = 0; i < 4; ++i) {
    int rl = wr + i * 16 + (lane >> 4) * 4;
    int grow = mtile * 128 + rl;
#pragma unroll
    for (int j = 0; j < 4; ++j) {
      int gcol = ntile * 128 + wc + j * 16 + (lane & 15);
#pragma unroll
      for (int q2 = 0; q2 < 4; ++q2) {
        if (grow + q2 < NN) {
          size_t idx = ((size_t)b * NN + grow + q2) * HH + gcol;
          float v = sum[i][j][q2];
          if (accflag) v += part[idx];
          part[idx] = v;
        }
      }
    }
  }
}

// -------- LayerNorm over H of z = relu(sum_g partial[g]) / R --------
__global__ __launch_bounds__(256) void lnorm(const float* __restrict__ partials, size_t psz, int np,
                                             _Float16* __restrict__ x16, float* __restrict__ out) {
  int row = blockIdx.x;
  int t = threadIdx.x;
  float v[3];
  float s = 0.f, s2 = 0.f;
#pragma unroll
  for (int j = 0; j < 3; ++j) {
    float a = 0.f;
    for (int gidx = 0; gidx < np; ++gidx) a += partials[(size_t)gidx * psz + (size_t)row * HH + t + j * 256];
    v[j] = fmaxf(a, 0.f) * (1.0f / RR);
    s += v[j];
    s2 += v[j] * v[j];
  }
#pragma unroll
  for (int o = 32; o; o >>= 1) {
    s += __shfl_xor(s, o);
    s2 += __shfl_xor(s2, o);
  }
  __shared__ float rs_[4], rs2_[4];
  int lane = t & 63, wid = t >> 6;
  if (!lane) { rs_[wid] = s; rs2_[wid] = s2; }
  __syncthreads();
  s = rs_[0] + rs_[1] + rs_[2] + rs_[3];
  s2 = rs2_[0] + rs2_[1] + rs2_[2] + rs2_[3];
  float mu = s * (1.0f / HH);
  float var = s2 * (1.0f / HH) - mu * mu;
  float rstd = rsqrtf(var + 1e-5f);
#pragma unroll
  for (int j = 0; j < 3; ++j) {
    float o = (v[j] - mu) * rstd;
    out[(size_t)row * HH + t + j * 256] = o;
    x16[(size_t)row * HH + t + j * 256] = (_Float16)o;
  }
}

extern "C" void kernel_launch(void* const* d_in, const int* in_sizes, int n_in,
                              void* d_out, int out_size, void* d_ws, size_t ws_size,
                              hipStream_t stream) {
  const float* adj = (const float*)d_in[0];
  const float* feature = (const float*)d_in[1];
  const float* dmask = (const float*)d_in[2];
  const float* W = (const float*)d_in[3];
  float* out = (float*)d_out;

  uintptr_t base = (uintptr_t)d_ws;
  uintptr_t p = base;
  auto alloc = [&](size_t bytes) -> void* {
    uintptr_t q = (p + 255) & ~(uintptr_t)255;
    p = q + bytes;
    return (void*)q;
  };
  _Float16* att = (_Float16*)alloc((size_t)BS * RR * NN * MPAD * 2);  // 122.5 MB
  _Float16* Wt = (_Float16*)alloc((size_t)2 * RR * HH * HH * 2);      // 108.5 MB
  _Float16* x16 = (_Float16*)alloc((size_t)MFLAT * HH * 2);           // 4.9 MB
  size_t psz = (size_t)MFLAT * HH;
  float* partials = (float*)alloc(4 * psz * 4);                       // 39.3 MB
  size_t used = p - base;
  size_t perR = (size_t)HH * LDW * 2;                                 // 4.94 MB / r
  size_t avail = ws_size > used ? ws_size - used : 0;
  int RCmax = (int)(avail / perR);
  if (RCmax > RR) RCmax = RR;
  if (RCmax < 1) RCmax = 1;
  _Float16* h1T = (_Float16*)alloc((size_t)RCmax * perR);

  conv_w<<<dim3(576, 2 * RR), 256, 0, stream>>>(W, Wt);
  conv_x<<<(MFLAT * HH / 4 + 255) / 256, 256, 0, stream>>>(feature, x16);
  att_softmax<<<dim3(NN, BS), 512, 0, stream>>>(adj, dmask, att);

  for (int layer = 0; layer < 2; ++layer) {
    if (RCmax >= RR) {
      gemm_xw<<<150 * RR, 256, 0, stream>>>(x16, Wt, h1T, layer, 0, 0);
      gemm_att<<<24 * 4 * BS, 256, 0, stream>>>(att, h1T, partials, psz, 0, 12, RR, 0, 0, 4);
      lnorm<<<MFLAT, 256, 0, stream>>>(partials, psz, 4, x16, out);
    } else {
      for (int r0 = 0; r0 < RR; r0 += RCmax) {
        int rc = RR - r0 < RCmax ? RR - r0 : RCmax;
        gemm_xw<<<150 * rc, 256, 0, stream>>>(x16, Wt, h1T, layer, r0, r0);
        gemm_att<<<24 * 1 * BS, 256, 0, stream>>>(att, h1T, partials, psz, r0, rc, r0 + rc, r0, r0 > 0, 1);
      }
      lnorm<<<MFLAT, 256, 0, stream>>>(partials, psz, 1, x16, out);
    }
  }
}

// Round 4
// 1126.935 us; speedup vs baseline: 1.6799x; 1.0758x over previous
//
#include <hip/hip_runtime.h>
#include <stdint.h>

#define BS 8
#define NN 400
#define HH 768
#define RR 46
#define MPAD 416
#define MFLAT2 3328  // 8 * 416: per-b padded flat M (416*2B = 832B, 64B-aligned)
#define LDW2 3328    // h1T row width == MFLAT2
#define PADM 402     // LDS row pad for softmax

typedef _Float16 half8 __attribute__((ext_vector_type(8)));
typedef _Float16 half4v __attribute__((ext_vector_type(4)));
typedef float floatx4 __attribute__((ext_vector_type(4)));

__device__ __forceinline__ void async16(const void* g, void* l) {
  __builtin_amdgcn_global_load_lds((const __attribute__((address_space(1))) uint32_t*)g,
                                   (__attribute__((address_space(3))) uint32_t*)l, 16, 0, 0);
}

// bijective XCD swizzle (m204)
__device__ __forceinline__ int xcd_work(int flat, int nwg) {
  int q = nwg >> 3, rem = nwg & 7;
  int xcd = flat & 7, slot = flat >> 3;
  return (xcd < rem ? xcd * (q + 1) : rem * (q + 1) + (xcd - rem) * q) + slot;
}

// counted vmcnt: ahead = number of 4-load stage-groups allowed to stay in flight
__device__ __forceinline__ void vm_wait(int ahead) {
  if (ahead >= 2) asm volatile("s_waitcnt vmcnt(8)" ::: "memory");
  else if (ahead == 1) asm volatile("s_waitcnt vmcnt(4)" ::: "memory");
  else asm volatile("s_waitcnt vmcnt(0)" ::: "memory");
}
#define BAR_TOP() { __builtin_amdgcn_s_barrier(); __builtin_amdgcn_sched_barrier(0); }
#define BAR_BOT() { asm volatile("s_waitcnt lgkmcnt(0)" ::: "memory"); \
                    __builtin_amdgcn_s_barrier(); __builtin_amdgcn_sched_barrier(0); }

// Stage a 128x32 fp16 tile (K-contiguous global layout) into LDS, linear.
__device__ __forceinline__ void stage_tile(const _Float16* __restrict__ g, int ld, int rowbase,
                                           int maxrow, int kbase, _Float16* lds, int t) {
  int w = t >> 6, lane = t & 63;
#pragma unroll
  for (int j = 0; j < 2; ++j) {
    int chunk = w * 2 + j;
    int eo = chunk * 512 + lane * 8;
    int row = eo >> 5;  // BK=32
    int col = eo & 31;
    int grow = rowbase + row;
    grow = grow > maxrow ? maxrow : grow;
    async16(g + (size_t)grow * ld + kbase + col, lds + chunk * 512);
  }
}

// One K-step: 8 ds_read_b128 + 16 MFMA per wave.
__device__ __forceinline__ void mma_tiles(const _Float16* As, const _Float16* Bs, int lane,
                                          int wr, int wc, floatx4 acc[4][4]) {
  int arow = wr + (lane & 15);
  int brow = wc + (lane & 15);
  int kcol = (lane >> 4) * 8;
  half8 a[4], b[4];
#pragma unroll
  for (int i = 0; i < 4; ++i) a[i] = *(const half8*)&As[(arow + i * 16) * 32 + kcol];
#pragma unroll
  for (int i = 0; i < 4; ++i) b[i] = *(const half8*)&Bs[(brow + i * 16) * 32 + kcol];
#pragma unroll
  for (int i = 0; i < 4; ++i)
#pragma unroll
    for (int j = 0; j < 4; ++j)
      acc[i][j] = __builtin_amdgcn_mfma_f32_16x16x32_f16(a[i], b[j], acc[i][j], 0, 0, 0);
}

// -------- W convert + transpose: W[l][r][h][k] (f32) -> Wt[l][r][k][h] (f16) --------
__global__ __launch_bounds__(256) void conv_w(const float* __restrict__ W, _Float16* __restrict__ Wt) {
  __shared__ float tl[32][33];
  int t = threadIdx.x;
  int lr = blockIdx.y;
  int tr = blockIdx.x / 24, tc = blockIdx.x % 24;
  const float* src = W + (size_t)lr * HH * HH;
  _Float16* dst = Wt + (size_t)lr * HH * HH;
  int rl = t >> 5, cl = t & 31;
#pragma unroll
  for (int j = 0; j < 4; ++j)
    tl[rl + 8 * j][cl] = src[(size_t)(tr * 32 + rl + 8 * j) * HH + tc * 32 + cl];
  __syncthreads();
#pragma unroll
  for (int j = 0; j < 4; ++j)
    dst[(size_t)(tc * 32 + rl + 8 * j) * HH + tr * 32 + cl] = (_Float16)tl[cl][rl + 8 * j];
}

// feature[b*400+m][h] f32 -> x16[b*416+m][h] f16, pad rows zeroed
__global__ void conv_x(const float* __restrict__ f, _Float16* __restrict__ x16) {
  int i4 = blockIdx.x * 256 + threadIdx.x;  // float4 index; grid covers exactly MFLAT2*HH/4
  int row = i4 / 192;                       // HH/4 = 192
  int c4 = i4 - row * 192;
  int b = row / 416;
  int m = row - b * 416;
  half4v h = {};
  if (m < NN) {
    float4 v = *(const float4*)(f + ((size_t)(b * NN + m) * HH) + c4 * 4);
    h[0] = (_Float16)v.x; h[1] = (_Float16)v.y; h[2] = (_Float16)v.z; h[3] = (_Float16)v.w;
  }
  *(half4v*)&x16[(size_t)row * HH + c4 * 4] = h;
}

// -------- softmax: no-max-pass (logits in [0,1] or masked->0), exp at staging --------
__global__ __launch_bounds__(512) void att_softmax(const float* __restrict__ adj,
                                                   const float* __restrict__ dmask,
                                                   _Float16* __restrict__ att) {
  __shared__ _Float16 sE[RR * PADM];
  __shared__ float sM[NN];
  int t = threadIdx.x;
  int n = blockIdx.x, b = blockIdx.y;
  const float* arow = adj + ((size_t)b * NN + n) * NN * RR;
  for (int i = t; i < NN; i += 512) sM[i] = dmask[b * NN + i];
  __syncthreads();
  for (int e0 = t * 4; e0 < NN * RR; e0 += 2048) {
    float4 v = *(const float4*)(arow + e0);
    float vv[4] = {v.x, v.y, v.z, v.w};
#pragma unroll
    for (int j = 0; j < 4; ++j) {
      int e = e0 + j;
      int m = e / RR;
      int r = e - m * RR;
      float val = sM[m] > 0.5f ? __expf(vv[j]) : 0.0f;
      sE[r * PADM + m] = (_Float16)val;
    }
  }
  __syncthreads();
  int lane = t & 63, wid = t >> 6;
  for (int r = wid; r < RR; r += 8) {
    const _Float16* row = &sE[r * PADM];
    float s = 0.f;
    for (int m = lane; m < NN; m += 64) s += (float)row[m];
#pragma unroll
    for (int o = 32; o; o >>= 1) s += __shfl_xor(s, o);
    float inv = 1.0f / s;
    _Float16* orow = att + (((size_t)b * RR + r) * NN + n) * MPAD;
    for (int m2 = lane * 2; m2 < MPAD; m2 += 128) {
      _Float16 lo = (_Float16)0.f, hi = (_Float16)0.f;
      if (m2 < NN) lo = (_Float16)((float)row[m2] * inv);
      if (m2 + 1 < NN) hi = (_Float16)((float)row[m2 + 1] * inv);
      union { _Float16 h[2]; uint32_t u; } pk;
      pk.h[0] = lo; pk.h[1] = hi;
      *(uint32_t*)&orow[m2] = pk.u;
    }
  }
}

// -------- GEMM C: h1T[r][k][gm] = (x @ W_r)^T; ring3 + counted-vmcnt pipeline --------
__global__ __launch_bounds__(256) void gemm_xw(const _Float16* __restrict__ x16,
                                               const _Float16* __restrict__ Wt,
                                               _Float16* __restrict__ h1T, int layer, int r0, int rbase) {
  __shared__ __align__(16) char smraw[49152];  // 3 x (As 8K + Bs 8K); epilogue outl (34.8K) aliases
  int t = threadIdx.x;
  int work = xcd_work(blockIdx.x, gridDim.x);
  int r_i = work / 156;
  int rem = work - r_i * 156;
  int r = r0 + r_i;
  int mtile = rem / 6, ntile = rem % 6;  // 26 x 6
  const _Float16* A = x16;
  const _Float16* Bp = Wt + ((size_t)layer * RR + r) * HH * HH;
  int lane = t & 63, w = t >> 6;
  int wr = (w >> 1) * 64, wc = (w & 1) * 64;
  floatx4 acc[4][4] = {};
  stage_tile(A, HH, mtile * 128, MFLAT2 - 1, 0, (_Float16*)smraw, t);
  stage_tile(Bp, HH, ntile * 128, HH - 1, 0, (_Float16*)(smraw + 8192), t);
  stage_tile(A, HH, mtile * 128, MFLAT2 - 1, 32, (_Float16*)(smraw + 16384), t);
  stage_tile(Bp, HH, ntile * 128, HH - 1, 32, (_Float16*)(smraw + 24576), t);
  int cur = 0, stb = 2;
  for (int ks = 0; ks < 24; ++ks) {
    if (ks + 2 < 24) {
      char* nb = smraw + stb * 16384;
      stage_tile(A, HH, mtile * 128, MFLAT2 - 1, (ks + 2) * 32, (_Float16*)nb, t);
      stage_tile(Bp, HH, ntile * 128, HH - 1, (ks + 2) * 32, (_Float16*)(nb + 8192), t);
      stb = stb == 2 ? 0 : stb + 1;
    }
    vm_wait(ks + 2 < 24 ? 2 : (ks + 1 < 24 ? 1 : 0));
    BAR_TOP();
    char* cb = smraw + cur * 16384;
    mma_tiles((const _Float16*)cb, (const _Float16*)(cb + 8192), lane, wr, wc, acc);
    BAR_BOT();
    cur = cur == 2 ? 0 : cur + 1;
  }
  _Float16* outl = (_Float16*)smraw;  // aliases staging (all consumed, vmcnt drained)
#pragma unroll
  for (int i = 0; i < 4; ++i) {
#pragma unroll
    for (int j = 0; j < 4; ++j) {
      int rl = wr + i * 16 + (lane >> 4) * 4;
      int cl = wc + j * 16 + (lane & 15);
      half4v v = {(_Float16)acc[i][j][0], (_Float16)acc[i][j][1],
                  (_Float16)acc[i][j][2], (_Float16)acc[i][j][3]};
      *(half4v*)&outl[cl * 136 + rl] = v;
    }
  }
  __syncthreads();
  _Float16* outp = h1T + (size_t)(r - rbase) * HH * LDW2;
#pragma unroll
  for (int pass = 0; pass < 8; ++pass) {
    int c = pass * 16 + (t >> 4);
    int ml = (t & 15) * 8;
    int gm = mtile * 128 + ml;
    int gn = ntile * 128 + c;
    half8 v = *(const half8*)&outl[c * 136 + ml];
    *(half8*)&outp[(size_t)gn * LDW2 + gm] = v;
  }
}

// -------- GEMM D: streaming r-group, ring3 + counted-vmcnt; no atomics --------
__global__ __launch_bounds__(256) void gemm_att(const _Float16* __restrict__ att,
                                                const _Float16* __restrict__ h1T,
                                                float* __restrict__ partials, size_t psz,
                                                int rs, int rcount, int rbase, int accflag,
                                                int ngroups) {
  __shared__ __align__(16) char smraw[49152];
  int t = threadIdx.x;
  int work = xcd_work(blockIdx.x, gridDim.x);
  int ntile = work % 6;
  int tmp = work / 6;
  int mtile = tmp & 3; tmp >>= 2;
  int g = tmp % ngroups;
  int b = tmp / ngroups;
  int rbeg = rs + (g * rcount) / ngroups;
  int rend = rs + ((g + 1) * rcount) / ngroups;
  int nr = rend - rbeg;
  float* part = partials + (size_t)g * psz;
  int lane = t & 63, w = t >> 6;
  int wr = (w >> 1) * 64, wc = (w & 1) * 64;
  floatx4 acc[4][4] = {}, sum[4][4] = {};
  const _Float16* A0 = att + ((size_t)b * RR + rbeg) * NN * MPAD;
  const _Float16* B0 = h1T + (size_t)(rbeg - rbase) * HH * LDW2 + b * MPAD;
  int total = nr * 13;
  // prologue: stage steps 0,1
  stage_tile(A0, MPAD, mtile * 128, NN - 1, 0, (_Float16*)smraw, t);
  stage_tile(B0, LDW2, ntile * 128, HH - 1, 0, (_Float16*)(smraw + 8192), t);
  stage_tile(A0, MPAD, mtile * 128, NN - 1, 32, (_Float16*)(smraw + 16384), t);
  stage_tile(B0, LDW2, ntile * 128, HH - 1, 32, (_Float16*)(smraw + 24576), t);
  const _Float16* nsA = A0;
  const _Float16* nsB = B0;
  int nsk = 2, cks = 0, cur = 0, stb = 2;
  if (total == 2) { nsk = 0; nsA += (size_t)NN * MPAD; nsB += (size_t)HH * LDW2; }
  for (int s = 0; s < total; ++s) {
    if (s + 2 < total) {
      char* nb = smraw + stb * 16384;
      stage_tile(nsA, MPAD, mtile * 128, NN - 1, nsk * 32, (_Float16*)nb, t);
      stage_tile(nsB, LDW2, ntile * 128, HH - 1, nsk * 32, (_Float16*)(nb + 8192), t);
      stb = stb == 2 ? 0 : stb + 1;
      if (++nsk == 13) { nsk = 0; nsA += (size_t)NN * MPAD; nsB += (size_t)HH * LDW2; }
    }
    vm_wait(s + 2 < total ? 2 : (s + 1 < total ? 1 : 0));
    BAR_TOP();
    char* cb = smraw + cur * 16384;
    mma_tiles((const _Float16*)cb, (const _Float16*)(cb + 8192), lane, wr, wc, acc);
    if (cks == 12) {
#pragma unroll
      for (int i = 0; i < 4; ++i)
#pragma unroll
        for (int j = 0; j < 4; ++j) {
#pragma unroll
          for (int q2 = 0; q2 < 4; ++q2) sum[i][j][q2] += fmaxf(acc[i][j][q2], 0.0f);
          acc[i][j] = (floatx4){0.f, 0.f, 0.f, 0.f};
        }
    }
    BAR_BOT();
    cur = cur == 2 ? 0 : cur + 1;
    cks = cks == 12 ? 0 : cks + 1;
  }
#pragma unroll
  for (int i = 0; i < 4; ++i) {
    int rl = wr + i * 16 + (lane >> 4) * 4;
    int grow = mtile * 128 + rl;
#pragma unroll
    for (int j = 0; j < 4; ++j) {
      int gcol = ntile * 128 + wc + j * 16 + (lane & 15);
#pragma unroll
      for (int q2 = 0; q2 < 4; ++q2) {
        if (grow + q2 < NN) {
          size_t idx = ((size_t)b * NN + grow + q2) * HH + gcol;
          float v = sum[i][j][q2];
          if (accflag) v += part[idx];
          part[idx] = v;
        }
      }
    }
  }
}

// -------- LayerNorm over H of z = relu(sum_g partial[g]) / R --------
__global__ __launch_bounds__(256) void lnorm(const float* __restrict__ partials, size_t psz, int np,
                                             _Float16* __restrict__ x16, float* __restrict__ out) {
  int row = blockIdx.x;  // 0..3199 flat b*400+n
  int t = threadIdx.x;
  int b = row / NN;
  int xrow = row + b * 16;  // b*416 + n
  float v[3];
  float s = 0.f, s2 = 0.f;
#pragma unroll
  for (int j = 0; j < 3; ++j) {
    float a = 0.f;
    for (int gidx = 0; gidx < np; ++gidx) a += partials[(size_t)gidx * psz + (size_t)row * HH + t + j * 256];
    v[j] = fmaxf(a, 0.f) * (1.0f / RR);
    s += v[j];
    s2 += v[j] * v[j];
  }
#pragma unroll
  for (int o = 32; o; o >>= 1) {
    s += __shfl_xor(s, o);
    s2 += __shfl_xor(s2, o);
  }
  __shared__ float rs_[4], rs2_[4];
  int lane = t & 63, wid = t >> 6;
  if (!lane) { rs_[wid] = s; rs2_[wid] = s2; }
  __syncthreads();
  s = rs_[0] + rs_[1] + rs_[2] + rs_[3];
  s2 = rs2_[0] + rs2_[1] + rs2_[2] + rs2_[3];
  float mu = s * (1.0f / HH);
  float var = s2 * (1.0f / HH) - mu * mu;
  float rstd = rsqrtf(var + 1e-5f);
#pragma unroll
  for (int j = 0; j < 3; ++j) {
    float o = (v[j] - mu) * rstd;
    out[(size_t)row * HH + t + j * 256] = o;
    x16[(size_t)xrow * HH + t + j * 256] = (_Float16)o;
  }
}

extern "C" void kernel_launch(void* const* d_in, const int* in_sizes, int n_in,
                              void* d_out, int out_size, void* d_ws, size_t ws_size,
                              hipStream_t stream) {
  const float* adj = (const float*)d_in[0];
  const float* feature = (const float*)d_in[1];
  const float* dmask = (const float*)d_in[2];
  const float* W = (const float*)d_in[3];
  float* out = (float*)d_out;

  uintptr_t base = (uintptr_t)d_ws;
  uintptr_t p = base;
  auto alloc = [&](size_t bytes) -> void* {
    uintptr_t q = (p + 255) & ~(uintptr_t)255;
    p = q + bytes;
    return (void*)q;
  };
  _Float16* att = (_Float16*)alloc((size_t)BS * RR * NN * MPAD * 2);  // 122.5 MB
  _Float16* Wt = (_Float16*)alloc((size_t)2 * RR * HH * HH * 2);      // 108.5 MB
  _Float16* x16 = (_Float16*)alloc((size_t)MFLAT2 * HH * 2);          // 5.1 MB
  size_t psz = (size_t)(BS * NN) * HH;
  float* partials = (float*)alloc(4 * psz * 4);                       // 39.3 MB
  size_t used = p - base;
  size_t perR = (size_t)HH * LDW2 * 2;                                // 5.11 MB / r
  size_t avail = ws_size > used ? ws_size - used : 0;
  int RCmax = (int)(avail / perR);
  if (RCmax > RR) RCmax = RR;
  if (RCmax < 1) RCmax = 1;
  _Float16* h1T = (_Float16*)alloc((size_t)RCmax * perR);

  conv_w<<<dim3(576, 2 * RR), 256, 0, stream>>>(W, Wt);
  conv_x<<<MFLAT2 * HH / 4 / 256, 256, 0, stream>>>(feature, x16);
  att_softmax<<<dim3(NN, BS), 512, 0, stream>>>(adj, dmask, att);

  for (int layer = 0; layer < 2; ++layer) {
    if (RCmax >= RR) {
      gemm_xw<<<156 * RR, 256, 0, stream>>>(x16, Wt, h1T, layer, 0, 0);
      gemm_att<<<24 * 4 * BS, 256, 0, stream>>>(att, h1T, partials, psz, 0, RR, 0, 0, 4);
      lnorm<<<BS * NN, 256, 0, stream>>>(partials, psz, 4, x16, out);
    } else {
      for (int r0 = 0; r0 < RR; r0 += RCmax) {
        int rc = RR - r0 < RCmax ? RR - r0 : RCmax;
        gemm_xw<<<156 * rc, 256, 0, stream>>>(x16, Wt, h1T, layer, r0, r0);
        gemm_att<<<24 * 1 * BS, 256, 0, stream>>>(att, h1T, partials, psz, r0, rc, r0, r0 > 0, 1);
      }
      lnorm<<<BS * NN, 256, 0, stream>>>(partials, psz, 1, x16, out);
    }
  }
}